// Round 1
// baseline (5300.870 us; speedup 1.0000x reference)
//
#include <hip/hip_runtime.h>
#include <hip/hip_bf16.h>

#define WAVE 64

// ---------------- graph preprocessing ----------------

__global__ void deg_kernel(const int* __restrict__ col, int* __restrict__ deg, int E) {
    int e = blockIdx.x * blockDim.x + threadIdx.x;
    if (e < E) atomicAdd(&deg[col[e]], 1);
}

__global__ void dinv_kernel(const int* __restrict__ deg, float* __restrict__ dinv, int N) {
    int n = blockIdx.x * blockDim.x + threadIdx.x;
    if (n < N) {
        int d = deg[n];
        dinv[n] = d > 0 ? rsqrtf((float)d) : 0.0f;
    }
}

// 3-phase exclusive scan over deg[N] -> rowptr[N+1], chunk = 512
__global__ void scan_phaseA(const int* __restrict__ deg, int* __restrict__ chunkSum, int N) {
    int t = threadIdx.x;
    int idx = blockIdx.x * 512 + t;
    int v = idx < N ? deg[idx] : 0;
    for (int o = 32; o > 0; o >>= 1) v += __shfl_down(v, o, 64);
    __shared__ int wsum[8];
    if ((t & 63) == 0) wsum[t >> 6] = v;
    __syncthreads();
    if (t == 0) {
        int s = 0;
        for (int i = 0; i < 8; ++i) s += wsum[i];
        chunkSum[blockIdx.x] = s;
    }
}

__global__ void scan_phaseB(const int* __restrict__ chunkSum, int* __restrict__ chunkOff, int n) {
    __shared__ int a[256], b[256];
    int t = threadIdx.x;
    int v = t < n ? chunkSum[t] : 0;
    a[t] = v;
    __syncthreads();
    int* s = a; int* d = b;
    for (int off = 1; off < 256; off <<= 1) {
        int x = s[t];
        if (t >= off) x += s[t - off];
        d[t] = x;
        __syncthreads();
        int* tmp = s; s = d; d = tmp;
    }
    if (t < n) chunkOff[t] = s[t] - v;
}

__global__ void scan_phaseC(const int* __restrict__ deg, const int* __restrict__ chunkOff,
                            int* __restrict__ rowptr, int N, int E) {
    __shared__ int a[512], b[512];
    int t = threadIdx.x;
    int idx = blockIdx.x * 512 + t;
    int v = idx < N ? deg[idx] : 0;
    a[t] = v;
    __syncthreads();
    int* s = a; int* d = b;
    for (int off = 1; off < 512; off <<= 1) {
        int x = s[t];
        if (t >= off) x += s[t - off];
        d[t] = x;
        __syncthreads();
        int* tmp = s; s = d; d = tmp;
    }
    if (idx < N) rowptr[idx] = chunkOff[blockIdx.x] + s[t] - v;
    if (idx == 0) rowptr[N] = E;
}

__global__ void fill_kernel(const int* __restrict__ row, const int* __restrict__ col,
                            const int* __restrict__ rowptr, int* __restrict__ cursor,
                            const float* __restrict__ dinv,
                            int* __restrict__ srcs, float* __restrict__ wsrt, int E) {
    int e = blockIdx.x * blockDim.x + threadIdx.x;
    if (e < E) {
        int dn = col[e];
        int p = rowptr[dn] + atomicAdd(&cursor[dn], 1);
        int s = row[e];
        srcs[p] = s;
        wsrt[p] = dinv[s];
    }
}

// ---------------- dense / propagation ----------------

// out = h @ W   (wave-per-node, W staged in LDS)
__global__ __launch_bounds__(256) void gemm_init_kernel(const float* __restrict__ h,
                                                        const float* __restrict__ W,
                                                        float* __restrict__ out, int n) {
    __shared__ float Wl[4096];
    for (int i = threadIdx.x; i < 4096; i += 256) Wl[i] = W[i];
    __syncthreads();
    int lane = threadIdx.x & 63;
    int gw = (blockIdx.x * blockDim.x + threadIdx.x) >> 6;
    int nw = (gridDim.x * blockDim.x) >> 6;
    for (int d = gw; d < n; d += nw) {
        float v = h[(size_t)d * 64 + lane];
        float o = 0.f;
#pragma unroll
        for (int i = 0; i < 64; ++i) o += __shfl(v, i, 64) * Wl[i * 64 + lane];
        out[(size_t)d * 64 + lane] = o;
    }
}

// out = h @ W + b   (final head)
__global__ __launch_bounds__(256) void gemm_bias_kernel(const float* __restrict__ h,
                                                        const float* __restrict__ W,
                                                        const float* __restrict__ b,
                                                        float* __restrict__ out, int n) {
    __shared__ float Wl[4096];
    for (int i = threadIdx.x; i < 4096; i += 256) Wl[i] = W[i];
    __syncthreads();
    int lane = threadIdx.x & 63;
    int gw = (blockIdx.x * blockDim.x + threadIdx.x) >> 6;
    int nw = (gridDim.x * blockDim.x) >> 6;
    for (int d = gw; d < n; d += nw) {
        float v = h[(size_t)d * 64 + lane];
        float o = b[lane];
#pragma unroll
        for (int i = 0; i < 64; ++i) o += __shfl(v, i, 64) * Wl[i * 64 + lane];
        out[(size_t)d * 64 + lane] = o;
    }
}

// one TAGConv hop, fused with its GEMM:
//   agg[d]   = dinv[d] * sum_{p in [rowptr[d],rowptr[d+1])} wsrt[p] * h_in[srcs[p]]
//   h_out[d] = agg[d]
//   out[d]  += agg[d] @ W
__global__ __launch_bounds__(256) void hop_kernel(const float* __restrict__ h_in,
                                                  const int* __restrict__ srcs,
                                                  const float* __restrict__ wsrt,
                                                  const int* __restrict__ rowptr,
                                                  const float* __restrict__ dinv,
                                                  const float* __restrict__ W,
                                                  float* __restrict__ out,
                                                  float* __restrict__ h_out, int n) {
    __shared__ float Wl[4096];
    for (int i = threadIdx.x; i < 4096; i += 256) Wl[i] = W[i];
    __syncthreads();
    int lane = threadIdx.x & 63;
    int gw = (blockIdx.x * blockDim.x + threadIdx.x) >> 6;
    int nw = (gridDim.x * blockDim.x) >> 6;
    for (int d = gw; d < n; d += nw) {
        int p0 = rowptr[d], p1 = rowptr[d + 1];
        float agg = 0.f;
        for (int p = p0; p < p1; ++p) {
            int s = srcs[p];
            float w = wsrt[p];
            agg += w * h_in[(size_t)s * 64 + lane];
        }
        agg *= dinv[d];
        h_out[(size_t)d * 64 + lane] = agg;
        float o = 0.f;
#pragma unroll
        for (int i = 0; i < 64; ++i) o += __shfl(agg, i, 64) * Wl[i * 64 + lane];
        out[(size_t)d * 64 + lane] += o;
    }
}

// h = tanh(acc + b)
__global__ void tanh_bias_kernel(const float* __restrict__ acc, const float* __restrict__ b,
                                 float* __restrict__ h, int total) {
    int i = blockIdx.x * blockDim.x + threadIdx.x;
    if (i < total) h[i] = tanhf(acc[i] + b[i & 63]);
}

// ---------------- launch ----------------

extern "C" void kernel_launch(void* const* d_in, const int* in_sizes, int n_in,
                              void* d_out, int out_size, void* d_ws, size_t ws_size,
                              hipStream_t stream) {
    const float* x  = (const float*)d_in[0];
    const int*   ei = (const int*)d_in[1];   // [2, E] int32
    const float* w1 = (const float*)d_in[2]; // [11,64,64]
    const float* b1 = (const float*)d_in[3];
    const float* w2 = (const float*)d_in[4]; // [4,64,64]
    const float* b2 = (const float*)d_in[5];
    const float* wc = (const float*)d_in[6];
    const float* bc = (const float*)d_in[7];
    float* out = (float*)d_out;

    const int N = in_sizes[0] / 64;
    const int E = in_sizes[1] / 2;
    const int K1 = 10, K2 = 3;
    const int* row = ei;
    const int* col = ei + E;

    // workspace carve (256B aligned)
    char* base = (char*)d_ws;
    auto alloc = [&](size_t bytes) { void* p = (void*)base; base += (bytes + 255) & ~(size_t)255; return p; };
    int*   deg      = (int*)alloc((size_t)N * 4);
    int*   cursor   = (int*)alloc((size_t)N * 4);
    int*   rowptr   = (int*)alloc((size_t)(N + 1) * 4);
    int*   chunkSum = (int*)alloc(256 * 4);
    int*   chunkOff = (int*)alloc(256 * 4);
    float* dinv     = (float*)alloc((size_t)N * 4);
    int*   srcs     = (int*)alloc((size_t)E * 4);
    float* wsrt     = (float*)alloc((size_t)E * 4);
    float* hA       = (float*)alloc((size_t)N * 64 * 4);
    float* hB       = (float*)alloc((size_t)N * 64 * 4);

    const int numChunks = (N + 511) / 512;
    const int eBlocks = (E + 255) / 256;
    const int nBlocks = (N + 255) / 256;
    const int tBlocks = (N * 64 + 255) / 256;
    const int gBlocks = 2048; // 8 blocks/CU, 32 waves/CU

    // ---- graph preprocessing ----
    hipMemsetAsync(deg, 0, (size_t)N * 4, stream);
    hipMemsetAsync(cursor, 0, (size_t)N * 4, stream);
    deg_kernel<<<eBlocks, 256, 0, stream>>>(col, deg, E);
    dinv_kernel<<<nBlocks, 256, 0, stream>>>(deg, dinv, N);
    scan_phaseA<<<numChunks, 512, 0, stream>>>(deg, chunkSum, N);
    scan_phaseB<<<1, 256, 0, stream>>>(chunkSum, chunkOff, numChunks);
    scan_phaseC<<<numChunks, 512, 0, stream>>>(deg, chunkOff, rowptr, N, E);
    fill_kernel<<<eBlocks, 256, 0, stream>>>(row, col, rowptr, cursor, dinv, srcs, wsrt, E);

    // ---- layer 1: tanh(TAGConv(x; w1, b1)), K1 hops ----
    gemm_init_kernel<<<gBlocks, 256, 0, stream>>>(x, w1, out, N);
    {
        const float* hin = x;
        float* bufs[2] = { hA, hB };
        for (int k = 1; k <= K1; ++k) {
            float* hout = bufs[(k - 1) & 1];
            hop_kernel<<<gBlocks, 256, 0, stream>>>(hin, srcs, wsrt, rowptr, dinv,
                                                    w1 + (size_t)k * 4096, out, hout, N);
            hin = hout;
        }
    }
    tanh_bias_kernel<<<tBlocks, 256, 0, stream>>>(out, b1, hA, N * 64);

    // ---- layer 2: tanh(TAGConv(hA; w2, b2)), K2 hops ----
    gemm_init_kernel<<<gBlocks, 256, 0, stream>>>(hA, w2, out, N);
    {
        const float* hin = hA;
        float* bufs[2] = { hB, hA }; // hop1 -> hB, hop2 -> hA, hop3 -> hB
        for (int k = 1; k <= K2; ++k) {
            float* hout = bufs[(k - 1) & 1];
            hop_kernel<<<gBlocks, 256, 0, stream>>>(hin, srcs, wsrt, rowptr, dinv,
                                                    w2 + (size_t)k * 4096, out, hout, N);
            hin = hout;
        }
    }
    tanh_bias_kernel<<<tBlocks, 256, 0, stream>>>(out, b2, hA, N * 64);

    // ---- head: hA @ wc + bc -> d_out ----
    gemm_bias_kernel<<<gBlocks, 256, 0, stream>>>(hA, wc, bc, out, N);
}

// Round 2
// 1970.458 us; speedup vs baseline: 2.6902x; 2.6902x over previous
//
#include <hip/hip_runtime.h>
#include <hip/hip_bf16.h>

#define WAVE 64
#define PAD 8   // pad each CSR segment to a multiple of 8 edges

// ---------------- graph preprocessing ----------------

__global__ void deg_kernel(const int* __restrict__ col, int* __restrict__ deg, int E) {
    int e = blockIdx.x * blockDim.x + threadIdx.x;
    if (e < E) atomicAdd(&deg[col[e]], 1);
}

__global__ void dinv_kernel(const int* __restrict__ deg, float* __restrict__ dinv, int N) {
    int n = blockIdx.x * blockDim.x + threadIdx.x;
    if (n < N) {
        int d = deg[n];
        dinv[n] = d > 0 ? rsqrtf((float)d) : 0.0f;
    }
}

__device__ __forceinline__ int pad_up(int v) { return (v + (PAD - 1)) & ~(PAD - 1); }

// 3-phase exclusive scan over padded deg -> rowptr[N+1], chunk = 512
__global__ void scan_phaseA(const int* __restrict__ deg, int* __restrict__ chunkSum, int N) {
    int t = threadIdx.x;
    int idx = blockIdx.x * 512 + t;
    int v = idx < N ? pad_up(deg[idx]) : 0;
    for (int o = 32; o > 0; o >>= 1) v += __shfl_down(v, o, 64);
    __shared__ int wsum[8];
    if ((t & 63) == 0) wsum[t >> 6] = v;
    __syncthreads();
    if (t == 0) {
        int s = 0;
        for (int i = 0; i < 8; ++i) s += wsum[i];
        chunkSum[blockIdx.x] = s;
    }
}

__global__ void scan_phaseB(const int* __restrict__ chunkSum, int* __restrict__ chunkOff, int n) {
    __shared__ int a[256], b[256];
    int t = threadIdx.x;
    int v = t < n ? chunkSum[t] : 0;
    a[t] = v;
    __syncthreads();
    int* s = a; int* d = b;
    for (int off = 1; off < 256; off <<= 1) {
        int x = s[t];
        if (t >= off) x += s[t - off];
        d[t] = x;
        __syncthreads();
        int* tmp = s; s = d; d = tmp;
    }
    if (t < n) chunkOff[t] = s[t] - v;
}

__global__ void scan_phaseC(const int* __restrict__ deg, const int* __restrict__ chunkOff,
                            int* __restrict__ rowptr, int N) {
    __shared__ int a[512], b[512];
    int t = threadIdx.x;
    int idx = blockIdx.x * 512 + t;
    int v = idx < N ? pad_up(deg[idx]) : 0;
    a[t] = v;
    __syncthreads();
    int* s = a; int* d = b;
    for (int off = 1; off < 512; off <<= 1) {
        int x = s[t];
        if (t >= off) x += s[t - off];
        d[t] = x;
        __syncthreads();
        int* tmp = s; s = d; d = tmp;
    }
    if (idx < N) rowptr[idx] = chunkOff[blockIdx.x] + s[t] - v;
    if (idx == N - 1) rowptr[N] = chunkOff[blockIdx.x] + s[t];  // total padded edges
}

__global__ void fill_kernel(const int* __restrict__ row, const int* __restrict__ col,
                            const int* __restrict__ rowptr, int* __restrict__ cursor,
                            const float* __restrict__ dinv,
                            int* __restrict__ srcs, float* __restrict__ wsrt, int E) {
    int e = blockIdx.x * blockDim.x + threadIdx.x;
    if (e < E) {
        int dn = col[e];
        int p = rowptr[dn] + atomicAdd(&cursor[dn], 1);
        int s = row[e];
        srcs[p] = s;
        wsrt[p] = dinv[s];
    }
}

// fill pad slots [rowptr[d]+deg[d], rowptr[d+1]) with dummy edges (src 0, w 0)
__global__ void pad_kernel(const int* __restrict__ deg, const int* __restrict__ rowptr,
                           int* __restrict__ srcs, float* __restrict__ wsrt, int N) {
    int dn = blockIdx.x * blockDim.x + threadIdx.x;
    if (dn < N) {
        int p = rowptr[dn] + deg[dn];
        int p1 = rowptr[dn + 1];
        for (; p < p1; ++p) { srcs[p] = 0; wsrt[p] = 0.0f; }
    }
}

// ---------------- dense / propagation ----------------

// out = h @ W   (wave-per-node, W staged in LDS)
__global__ __launch_bounds__(256) void gemm_init_kernel(const float* __restrict__ h,
                                                        const float* __restrict__ W,
                                                        float* __restrict__ out, int n) {
    __shared__ float Wl[4096];
    for (int i = threadIdx.x; i < 4096; i += 256) Wl[i] = W[i];
    __syncthreads();
    int lane = threadIdx.x & 63;
    int gw = (blockIdx.x * blockDim.x + threadIdx.x) >> 6;
    gw = __builtin_amdgcn_readfirstlane(gw);
    int nw = (gridDim.x * blockDim.x) >> 6;
    for (int d = gw; d < n; d += nw) {
        float v = h[(size_t)d * 64 + lane];
        float o = 0.f;
#pragma unroll
        for (int i = 0; i < 64; ++i) o += __shfl(v, i, 64) * Wl[i * 64 + lane];
        out[(size_t)d * 64 + lane] = o;
    }
}

// out = h @ W + b   (final head)
__global__ __launch_bounds__(256) void gemm_bias_kernel(const float* __restrict__ h,
                                                        const float* __restrict__ W,
                                                        const float* __restrict__ b,
                                                        float* __restrict__ out, int n) {
    __shared__ float Wl[4096];
    for (int i = threadIdx.x; i < 4096; i += 256) Wl[i] = W[i];
    __syncthreads();
    int lane = threadIdx.x & 63;
    int gw = (blockIdx.x * blockDim.x + threadIdx.x) >> 6;
    gw = __builtin_amdgcn_readfirstlane(gw);
    int nw = (gridDim.x * blockDim.x) >> 6;
    for (int d = gw; d < n; d += nw) {
        float v = h[(size_t)d * 64 + lane];
        float o = b[lane];
#pragma unroll
        for (int i = 0; i < 64; ++i) o += __shfl(v, i, 64) * Wl[i * 64 + lane];
        out[(size_t)d * 64 + lane] = o;
    }
}

// one TAGConv hop, fused with its GEMM. Edge lists are padded to PAD=8, so
// the gather loop runs in groups of 8 independent 256B loads (MLP=8).
__global__ __launch_bounds__(256) void hop_kernel(const float* __restrict__ h_in,
                                                  const int* __restrict__ srcs,
                                                  const float* __restrict__ wsrt,
                                                  const int* __restrict__ rowptr,
                                                  const float* __restrict__ dinv,
                                                  const float* __restrict__ W,
                                                  float* __restrict__ out,
                                                  float* __restrict__ h_out, int n) {
    __shared__ float Wl[4096];
    for (int i = threadIdx.x; i < 4096; i += 256) Wl[i] = W[i];
    __syncthreads();
    int lane = threadIdx.x & 63;
    int gw = (blockIdx.x * blockDim.x + threadIdx.x) >> 6;
    gw = __builtin_amdgcn_readfirstlane(gw);   // wave-uniform node index -> scalar metadata loads
    int nw = (gridDim.x * blockDim.x) >> 6;
    for (int d = gw; d < n; d += nw) {
        int p0 = rowptr[d], p1 = rowptr[d + 1];
        float agg = 0.f;
        for (int p = p0; p < p1; p += 8) {
            int s0 = srcs[p + 0], s1 = srcs[p + 1], s2 = srcs[p + 2], s3 = srcs[p + 3];
            int s4 = srcs[p + 4], s5 = srcs[p + 5], s6 = srcs[p + 6], s7 = srcs[p + 7];
            float w0 = wsrt[p + 0], w1 = wsrt[p + 1], w2 = wsrt[p + 2], w3 = wsrt[p + 3];
            float w4 = wsrt[p + 4], w5 = wsrt[p + 5], w6 = wsrt[p + 6], w7 = wsrt[p + 7];
            float v0 = h_in[(size_t)s0 * 64 + lane];
            float v1 = h_in[(size_t)s1 * 64 + lane];
            float v2 = h_in[(size_t)s2 * 64 + lane];
            float v3 = h_in[(size_t)s3 * 64 + lane];
            float v4 = h_in[(size_t)s4 * 64 + lane];
            float v5 = h_in[(size_t)s5 * 64 + lane];
            float v6 = h_in[(size_t)s6 * 64 + lane];
            float v7 = h_in[(size_t)s7 * 64 + lane];
            agg += w0 * v0; agg += w1 * v1; agg += w2 * v2; agg += w3 * v3;
            agg += w4 * v4; agg += w5 * v5; agg += w6 * v6; agg += w7 * v7;
        }
        agg *= dinv[d];
        h_out[(size_t)d * 64 + lane] = agg;
        float o = 0.f;
#pragma unroll
        for (int i = 0; i < 64; ++i) o += __shfl(agg, i, 64) * Wl[i * 64 + lane];
        out[(size_t)d * 64 + lane] += o;
    }
}

// h = tanh(acc + b)
__global__ void tanh_bias_kernel(const float* __restrict__ acc, const float* __restrict__ b,
                                 float* __restrict__ h, int total) {
    int i = blockIdx.x * blockDim.x + threadIdx.x;
    if (i < total) h[i] = tanhf(acc[i] + b[i & 63]);
}

// ---------------- launch ----------------

extern "C" void kernel_launch(void* const* d_in, const int* in_sizes, int n_in,
                              void* d_out, int out_size, void* d_ws, size_t ws_size,
                              hipStream_t stream) {
    const float* x  = (const float*)d_in[0];
    const int*   ei = (const int*)d_in[1];   // [2, E] int32
    const float* w1 = (const float*)d_in[2]; // [11,64,64]
    const float* b1 = (const float*)d_in[3];
    const float* w2 = (const float*)d_in[4]; // [4,64,64]
    const float* b2 = (const float*)d_in[5];
    const float* wc = (const float*)d_in[6];
    const float* bc = (const float*)d_in[7];
    float* out = (float*)d_out;

    const int N = in_sizes[0] / 64;
    const int E = in_sizes[1] / 2;
    const int K1 = 10, K2 = 3;
    const int* row = ei;
    const int* col = ei + E;
    const int Epad = E + (PAD - 1) * N + PAD; // upper bound on padded edge count

    // workspace carve (256B aligned)
    char* base = (char*)d_ws;
    auto alloc = [&](size_t bytes) { void* p = (void*)base; base += (bytes + 255) & ~(size_t)255; return p; };
    int*   deg      = (int*)alloc((size_t)N * 4);
    int*   cursor   = (int*)alloc((size_t)N * 4);
    int*   rowptr   = (int*)alloc((size_t)(N + 1) * 4);
    int*   chunkSum = (int*)alloc(256 * 4);
    int*   chunkOff = (int*)alloc(256 * 4);
    float* dinv     = (float*)alloc((size_t)N * 4);
    int*   srcs     = (int*)alloc((size_t)Epad * 4);
    float* wsrt     = (float*)alloc((size_t)Epad * 4);
    float* hA       = (float*)alloc((size_t)N * 64 * 4);
    float* hB       = (float*)alloc((size_t)N * 64 * 4);

    const int numChunks = (N + 511) / 512;
    const int eBlocks = (E + 255) / 256;
    const int nBlocks = (N + 255) / 256;
    const int tBlocks = (N * 64 + 255) / 256;
    const int gBlocks = 2048; // 8 blocks/CU, 32 waves/CU

    // ---- graph preprocessing ----
    hipMemsetAsync(deg, 0, (size_t)N * 4, stream);
    hipMemsetAsync(cursor, 0, (size_t)N * 4, stream);
    deg_kernel<<<eBlocks, 256, 0, stream>>>(col, deg, E);
    dinv_kernel<<<nBlocks, 256, 0, stream>>>(deg, dinv, N);
    scan_phaseA<<<numChunks, 512, 0, stream>>>(deg, chunkSum, N);
    scan_phaseB<<<1, 256, 0, stream>>>(chunkSum, chunkOff, numChunks);
    scan_phaseC<<<numChunks, 512, 0, stream>>>(deg, chunkOff, rowptr, N);
    fill_kernel<<<eBlocks, 256, 0, stream>>>(row, col, rowptr, cursor, dinv, srcs, wsrt, E);
    pad_kernel<<<nBlocks, 256, 0, stream>>>(deg, rowptr, srcs, wsrt, N);

    // ---- layer 1: tanh(TAGConv(x; w1, b1)), K1 hops ----
    gemm_init_kernel<<<gBlocks, 256, 0, stream>>>(x, w1, out, N);
    {
        const float* hin = x;
        float* bufs[2] = { hA, hB };
        for (int k = 1; k <= K1; ++k) {
            float* hout = bufs[(k - 1) & 1];
            hop_kernel<<<gBlocks, 256, 0, stream>>>(hin, srcs, wsrt, rowptr, dinv,
                                                    w1 + (size_t)k * 4096, out, hout, N);
            hin = hout;
        }
    }
    tanh_bias_kernel<<<tBlocks, 256, 0, stream>>>(out, b1, hA, N * 64);

    // ---- layer 2: tanh(TAGConv(hA; w2, b2)), K2 hops ----
    gemm_init_kernel<<<gBlocks, 256, 0, stream>>>(hA, w2, out, N);
    {
        const float* hin = hA;
        float* bufs[2] = { hB, hA }; // hop1 -> hB, hop2 -> hA, hop3 -> hB
        for (int k = 1; k <= K2; ++k) {
            float* hout = bufs[(k - 1) & 1];
            hop_kernel<<<gBlocks, 256, 0, stream>>>(hin, srcs, wsrt, rowptr, dinv,
                                                    w2 + (size_t)k * 4096, out, hout, N);
            hin = hout;
        }
    }
    tanh_bias_kernel<<<tBlocks, 256, 0, stream>>>(out, b2, hA, N * 64);

    // ---- head: hA @ wc + bc -> d_out ----
    gemm_bias_kernel<<<gBlocks, 256, 0, stream>>>(hA, wc, bc, out, N);
}

// Round 3
// 1701.304 us; speedup vs baseline: 3.1158x; 1.1582x over previous
//
#include <hip/hip_runtime.h>
#include <hip/hip_bf16.h>

#define PAD 8   // pad each CSR segment to a multiple of 8 edges

// ---------------- graph preprocessing ----------------

__global__ void deg_kernel(const int* __restrict__ col, int* __restrict__ deg, int E) {
    int e = blockIdx.x * blockDim.x + threadIdx.x;
    if (e < E) atomicAdd(&deg[col[e]], 1);
}

__global__ void dinv_kernel(const int* __restrict__ deg, float* __restrict__ dinv,
                            float* __restrict__ dinv2, int N) {
    int n = blockIdx.x * blockDim.x + threadIdx.x;
    if (n < N) {
        int d = deg[n];
        float v = d > 0 ? rsqrtf((float)d) : 0.0f;
        dinv[n] = v;
        dinv2[n] = v * v;
    }
}

__device__ __forceinline__ int pad_up(int v) { return (v + (PAD - 1)) & ~(PAD - 1); }

// 3-phase exclusive scan over padded deg -> rowptr[N+1], chunk = 512
__global__ void scan_phaseA(const int* __restrict__ deg, int* __restrict__ chunkSum, int N) {
    int t = threadIdx.x;
    int idx = blockIdx.x * 512 + t;
    int v = idx < N ? pad_up(deg[idx]) : 0;
    for (int o = 32; o > 0; o >>= 1) v += __shfl_down(v, o, 64);
    __shared__ int wsum[8];
    if ((t & 63) == 0) wsum[t >> 6] = v;
    __syncthreads();
    if (t == 0) {
        int s = 0;
        for (int i = 0; i < 8; ++i) s += wsum[i];
        chunkSum[blockIdx.x] = s;
    }
}

__global__ void scan_phaseB(const int* __restrict__ chunkSum, int* __restrict__ chunkOff, int n) {
    __shared__ int a[256], b[256];
    int t = threadIdx.x;
    int v = t < n ? chunkSum[t] : 0;
    a[t] = v;
    __syncthreads();
    int* s = a; int* d = b;
    for (int off = 1; off < 256; off <<= 1) {
        int x = s[t];
        if (t >= off) x += s[t - off];
        d[t] = x;
        __syncthreads();
        int* tmp = s; s = d; d = tmp;
    }
    if (t < n) chunkOff[t] = s[t] - v;
}

__global__ void scan_phaseC(const int* __restrict__ deg, const int* __restrict__ chunkOff,
                            int* __restrict__ rowptr, int N) {
    __shared__ int a[512], b[512];
    int t = threadIdx.x;
    int idx = blockIdx.x * 512 + t;
    int v = idx < N ? pad_up(deg[idx]) : 0;
    a[t] = v;
    __syncthreads();
    int* s = a; int* d = b;
    for (int off = 1; off < 512; off <<= 1) {
        int x = s[t];
        if (t >= off) x += s[t - off];
        d[t] = x;
        __syncthreads();
        int* tmp = s; s = d; d = tmp;
    }
    if (idx < N) rowptr[idx] = chunkOff[blockIdx.x] + s[t] - v;
    if (idx == N - 1) rowptr[N] = chunkOff[blockIdx.x] + s[t];  // total padded edges
}

// scatter only the source index (4B/edge) — weights are gone algebraically
__global__ void fill_kernel(const int* __restrict__ row, const int* __restrict__ col,
                            const int* __restrict__ rowptr, int* __restrict__ cursor,
                            int* __restrict__ srcs, int E) {
    int e = blockIdx.x * blockDim.x + threadIdx.x;
    if (e < E) {
        int dn = col[e];
        int p = rowptr[dn] + atomicAdd(&cursor[dn], 1);
        srcs[p] = row[e];
    }
}

// pad slots point at row N of g (kept all-zero)
__global__ void pad_kernel(const int* __restrict__ deg, const int* __restrict__ rowptr,
                           int* __restrict__ srcs, int N) {
    int dn = blockIdx.x * blockDim.x + threadIdx.x;
    if (dn < N) {
        int p = rowptr[dn] + deg[dn];
        int p1 = rowptr[dn + 1];
        for (; p < p1; ++p) srcs[p] = N;
    }
}

// g0 = bf16(dinv ⊙ x), plus zeroed pad row N
__global__ void cvt_g_kernel(const float* __restrict__ x, const float* __restrict__ dinv,
                             __hip_bfloat16* __restrict__ g, int N) {
    int i = blockIdx.x * blockDim.x + threadIdx.x;
    int total = (N + 1) * 64;
    if (i < total) {
        float v = (i < N * 64) ? dinv[i >> 6] * x[i] : 0.0f;
        g[i] = __float2bfloat16(v);
    }
}

// h = tanh(acc + b); g = bf16(dinv ⊙ h)
__global__ void tanh_g_kernel(const float* __restrict__ acc, const float* __restrict__ b,
                              const float* __restrict__ dinv, float* __restrict__ h,
                              __hip_bfloat16* __restrict__ g, int total) {
    int i = blockIdx.x * blockDim.x + threadIdx.x;
    if (i < total) {
        float v = tanhf(acc[i] + b[i & 63]);
        h[i] = v;
        g[i] = __float2bfloat16(dinv[i >> 6] * v);
    }
}

// ---------------- propagation ----------------

#define GATHER8(P)                                                                 \
    {                                                                              \
        int s0 = srcs[P + 0], s1 = srcs[P + 1], s2 = srcs[P + 2], s3 = srcs[P + 3];\
        int s4 = srcs[P + 4], s5 = srcs[P + 5], s6 = srcs[P + 6], s7 = srcs[P + 7];\
        float v0 = __bfloat162float(g_in[(size_t)s0 * 64 + lane]);                 \
        float v1 = __bfloat162float(g_in[(size_t)s1 * 64 + lane]);                 \
        float v2 = __bfloat162float(g_in[(size_t)s2 * 64 + lane]);                 \
        float v3 = __bfloat162float(g_in[(size_t)s3 * 64 + lane]);                 \
        float v4 = __bfloat162float(g_in[(size_t)s4 * 64 + lane]);                 \
        float v5 = __bfloat162float(g_in[(size_t)s5 * 64 + lane]);                 \
        float v6 = __bfloat162float(g_in[(size_t)s6 * 64 + lane]);                 \
        float v7 = __bfloat162float(g_in[(size_t)s7 * 64 + lane]);                 \
        u += v0; u += v1; u += v2; u += v3; u += v4; u += v5; u += v6; u += v7;    \
    }

// first hop of a layer, fused with both k=0 and k=1 GEMM terms; out is written (not RMW)
__global__ __launch_bounds__(256) void hop_first_kernel(
        const float* __restrict__ hdir, const __hip_bfloat16* __restrict__ g_in,
        const int* __restrict__ srcs, const int* __restrict__ rowptr,
        const float* __restrict__ dinv, const float* __restrict__ dinv2,
        const float* __restrict__ W0, const float* __restrict__ W1,
        float* __restrict__ out, __hip_bfloat16* __restrict__ g_out, int n) {
    __shared__ float W0l[4096];
    __shared__ float W1l[4096];
    for (int i = threadIdx.x; i < 4096; i += 256) { W0l[i] = W0[i]; W1l[i] = W1[i]; }
    __syncthreads();
    int lane = threadIdx.x & 63;
    int gw = __builtin_amdgcn_readfirstlane((blockIdx.x * blockDim.x + threadIdx.x) >> 6);
    int nw = (gridDim.x * blockDim.x) >> 6;
    for (int d = gw; d < n; d += nw) {
        int p0 = rowptr[d], p1 = rowptr[d + 1];
        float u = 0.f;
        for (int p = p0; p < p1; p += 8) GATHER8(p);
        float h0 = hdir[(size_t)d * 64 + lane];
        float h1 = dinv[d] * u;
        g_out[(size_t)d * 64 + lane] = __float2bfloat16(dinv2[d] * u);
        float o = 0.f;
#pragma unroll
        for (int i = 0; i < 64; ++i) {
            o += __shfl(h0, i, 64) * W0l[i * 64 + lane];
            o += __shfl(h1, i, 64) * W1l[i * 64 + lane];
        }
        out[(size_t)d * 64 + lane] = o;
    }
}

// middle hop: gather-sum, fused GEMM accumulate, write next g
__global__ __launch_bounds__(256) void hop_mid_kernel(
        const __hip_bfloat16* __restrict__ g_in,
        const int* __restrict__ srcs, const int* __restrict__ rowptr,
        const float* __restrict__ dinv, const float* __restrict__ dinv2,
        const float* __restrict__ W,
        float* __restrict__ out, __hip_bfloat16* __restrict__ g_out, int n) {
    __shared__ float Wl[4096];
    for (int i = threadIdx.x; i < 4096; i += 256) Wl[i] = W[i];
    __syncthreads();
    int lane = threadIdx.x & 63;
    int gw = __builtin_amdgcn_readfirstlane((blockIdx.x * blockDim.x + threadIdx.x) >> 6);
    int nw = (gridDim.x * blockDim.x) >> 6;
    for (int d = gw; d < n; d += nw) {
        int p0 = rowptr[d], p1 = rowptr[d + 1];
        float u = 0.f;
        for (int p = p0; p < p1; p += 8) GATHER8(p);
        float h = dinv[d] * u;
        g_out[(size_t)d * 64 + lane] = __float2bfloat16(dinv2[d] * u);
        float o = 0.f;
#pragma unroll
        for (int i = 0; i < 64; ++i) o += __shfl(h, i, 64) * Wl[i * 64 + lane];
        out[(size_t)d * 64 + lane] += o;
    }
}

// final: v = tanh(acc + b); out = v @ Wc + bc   (in-place safe: regs only between rd/wr)
__global__ __launch_bounds__(256) void tanh_gemm_bias_kernel(
        const float* __restrict__ acc, const float* __restrict__ b,
        const float* __restrict__ W, const float* __restrict__ bc,
        float* __restrict__ out, int n) {
    __shared__ float Wl[4096];
    for (int i = threadIdx.x; i < 4096; i += 256) Wl[i] = W[i];
    __syncthreads();
    int lane = threadIdx.x & 63;
    int gw = __builtin_amdgcn_readfirstlane((blockIdx.x * blockDim.x + threadIdx.x) >> 6);
    int nw = (gridDim.x * blockDim.x) >> 6;
    for (int d = gw; d < n; d += nw) {
        float v = tanhf(acc[(size_t)d * 64 + lane] + b[lane]);
        float o = bc[lane];
#pragma unroll
        for (int i = 0; i < 64; ++i) o += __shfl(v, i, 64) * Wl[i * 64 + lane];
        out[(size_t)d * 64 + lane] = o;
    }
}

// ---------------- launch ----------------

extern "C" void kernel_launch(void* const* d_in, const int* in_sizes, int n_in,
                              void* d_out, int out_size, void* d_ws, size_t ws_size,
                              hipStream_t stream) {
    const float* x  = (const float*)d_in[0];
    const int*   ei = (const int*)d_in[1];   // [2, E] int32
    const float* w1 = (const float*)d_in[2]; // [11,64,64]
    const float* b1 = (const float*)d_in[3];
    const float* w2 = (const float*)d_in[4]; // [4,64,64]
    const float* b2 = (const float*)d_in[5];
    const float* wc = (const float*)d_in[6];
    const float* bc = (const float*)d_in[7];
    float* out = (float*)d_out;

    const int N = in_sizes[0] / 64;
    const int E = in_sizes[1] / 2;
    const int K1 = 10, K2 = 3;
    const int* row = ei;
    const int* col = ei + E;
    const int Epad = E + (PAD - 1) * N + 64; // upper bound on padded edge count

    // workspace carve (256B aligned)
    char* base = (char*)d_ws;
    auto alloc = [&](size_t bytes) { void* p = (void*)base; base += (bytes + 255) & ~(size_t)255; return p; };
    int*   deg      = (int*)alloc((size_t)N * 4);
    int*   cursor   = (int*)alloc((size_t)N * 4);
    int*   rowptr   = (int*)alloc((size_t)(N + 1) * 4);
    int*   chunkSum = (int*)alloc(256 * 4);
    int*   chunkOff = (int*)alloc(256 * 4);
    float* dinv     = (float*)alloc((size_t)N * 4);
    float* dinv2    = (float*)alloc((size_t)N * 4);
    int*   srcs     = (int*)alloc((size_t)Epad * 4);
    __hip_bfloat16* gX = (__hip_bfloat16*)alloc((size_t)(N + 1) * 64 * 2);
    __hip_bfloat16* gA = (__hip_bfloat16*)alloc((size_t)(N + 1) * 64 * 2);
    __hip_bfloat16* gB = (__hip_bfloat16*)alloc((size_t)(N + 1) * 64 * 2);
    float* hA       = (float*)alloc((size_t)N * 64 * 4);

    const int numChunks = (N + 511) / 512;
    const int eBlocks = (E + 255) / 256;
    const int nBlocks = (N + 255) / 256;
    const int tBlocks = (N * 64 + 255) / 256;
    const int cBlocks = ((N + 1) * 64 + 255) / 256;
    const int gBlocks = 2048;

    // ---- graph preprocessing ----
    hipMemsetAsync(deg, 0, (size_t)N * 4, stream);
    hipMemsetAsync(cursor, 0, (size_t)N * 4, stream);
    hipMemsetAsync(gA + (size_t)N * 64, 0, 128, stream);  // pad row N stays zero
    hipMemsetAsync(gB + (size_t)N * 64, 0, 128, stream);
    deg_kernel<<<eBlocks, 256, 0, stream>>>(col, deg, E);
    dinv_kernel<<<nBlocks, 256, 0, stream>>>(deg, dinv, dinv2, N);
    scan_phaseA<<<numChunks, 512, 0, stream>>>(deg, chunkSum, N);
    scan_phaseB<<<1, 256, 0, stream>>>(chunkSum, chunkOff, numChunks);
    scan_phaseC<<<numChunks, 512, 0, stream>>>(deg, chunkOff, rowptr, N);
    fill_kernel<<<eBlocks, 256, 0, stream>>>(row, col, rowptr, cursor, srcs, E);
    pad_kernel<<<nBlocks, 256, 0, stream>>>(deg, rowptr, srcs, N);
    cvt_g_kernel<<<cBlocks, 256, 0, stream>>>(x, dinv, gX, N);

    // ---- layer 1: tanh(TAGConv(x; w1, b1)), K1 hops ----
    hop_first_kernel<<<gBlocks, 256, 0, stream>>>(x, gX, srcs, rowptr, dinv, dinv2,
                                                  w1, w1 + 4096, out, gA, N);
    {
        __hip_bfloat16* bufs[2] = { gA, gB };
        for (int k = 2; k <= K1; ++k) {
            __hip_bfloat16* gin  = bufs[k & 1];        // k=2: gA, k=3: gB, ...
            __hip_bfloat16* gout = bufs[(k + 1) & 1];
            hop_mid_kernel<<<gBlocks, 256, 0, stream>>>(gin, srcs, rowptr, dinv, dinv2,
                                                        w1 + (size_t)k * 4096, out, gout, N);
        }
    }
    tanh_g_kernel<<<tBlocks, 256, 0, stream>>>(out, b1, dinv, hA, gX, N * 64);

    // ---- layer 2: tanh(TAGConv(hA; w2, b2)), K2 hops ----
    hop_first_kernel<<<gBlocks, 256, 0, stream>>>(hA, gX, srcs, rowptr, dinv, dinv2,
                                                  w2, w2 + 4096, out, gA, N);
    {
        __hip_bfloat16* bufs[2] = { gA, gB };
        for (int k = 2; k <= K2; ++k) {
            __hip_bfloat16* gin  = bufs[k & 1];
            __hip_bfloat16* gout = bufs[(k + 1) & 1];
            hop_mid_kernel<<<gBlocks, 256, 0, stream>>>(gin, srcs, rowptr, dinv, dinv2,
                                                        w2 + (size_t)k * 4096, out, gout, N);
        }
    }

    // ---- tanh + head fused: d_out = tanh(out + b2) @ wc + bc ----
    tanh_gemm_bias_kernel<<<gBlocks, 256, 0, stream>>>(out, b2, wc, bc, out, N);
}